// Round 9
// baseline (251.633 us; speedup 1.0000x reference)
//
#include <hip/hip_runtime.h>

typedef _Float16 half8 __attribute__((ext_vector_type(8)));
typedef _Float16 half4v __attribute__((ext_vector_type(4)));
typedef float f32x4 __attribute__((ext_vector_type(4)));

#define ZQ_ELEMS 8388608   // 32*256*32*32
#define N_TOK    32768
#define D_DIM    256
#define K_CB     1024

#define FLAG_CAP 8192      // observed cnt ~730 (deterministic input); 11x margin
#define ESCALE   1024.0f
#define TAU      0.15f     // flag margin: ref f32-grid slack + fp16 noise + 0.004 encode noise

__device__ __align__(16) _Float16 g_eh[K_CB * D_DIM];  // fp16(1024*e)
__device__ __align__(16) float g_ebT[D_DIM * K_CB];    // emb transposed [d][k], 1 MB
__device__ float g_ck[K_CB];                            // 512*||e_k||^2 (prefilter)
__device__ float g_bk[K_CB];                            // f32(sum e^2), np-style B_k
__device__ float g_loss;
__device__ int   g_cnt;
__device__ int   g_flags[FLAG_CAP];
__device__ float g_zst[FLAG_CAP * 256];                 // staged z rows (coalesced)
__device__ float g_aA[FLAG_CAP];                        // A_n per flagged token
__device__ unsigned long long g_best[FLAG_CAP];         // (orderedD<<32)|k, atomicMin

__device__ __forceinline__ unsigned long long enc_dk(float D, int k) {
  unsigned int b = __float_as_uint(D);
  unsigned int u = (b & 0x80000000u) ? ~b : (b | 0x80000000u);  // order-preserving
  return (((unsigned long long)u) << 32) | (unsigned int)k;
}

// fused prep (blocks 0..255) + transpose (blocks 256..319)
__global__ __launch_bounds__(256) void vq_prep_tr(const float* __restrict__ emb) {
  __shared__ float tl[64][65];
  const int tid = threadIdx.x;
  if (blockIdx.x < 256) {
    const int w = tid >> 6, l = tid & 63;
    const int k = (blockIdx.x << 2) + w;
    f32x4 v = *(const f32x4*)(emb + (k << 8) + (l << 2));
    double sd = (double)v[0]*v[0] + (double)v[1]*v[1] + (double)v[2]*v[2] + (double)v[3]*v[3];
    #pragma unroll
    for (int m = 1; m < 64; m <<= 1) sd += __shfl_xor(sd, m);
    if (l == 0) { g_bk[k] = (float)sd; g_ck[k] = 512.0f * (float)sd; }
    half4v h;
    h[0] = (_Float16)(v[0] * ESCALE); h[1] = (_Float16)(v[1] * ESCALE);
    h[2] = (_Float16)(v[2] * ESCALE); h[3] = (_Float16)(v[3] * ESCALE);
    *(half4v*)(g_eh + (k << 8) + (l << 2)) = h;
    const int gi = blockIdx.x * 256 + tid;
    if (gi < FLAG_CAP) g_best[gi] = ~0ULL;
    if (blockIdx.x == 0 && tid == 0) { g_loss = 0.0f; g_cnt = 0; }
  } else {
    const int bid = blockIdx.x - 256;
    const int tx = tid & 63, ty = tid >> 6;
    const int k0 = (bid & 15) << 6;
    const int d0 = (bid >> 4) << 6;
    #pragma unroll
    for (int j = 0; j < 16; j++) {
      const int kk = (ty << 4) + j;
      tl[kk][tx] = emb[((k0 + kk) << 8) + d0 + tx];
    }
    __syncthreads();
    #pragma unroll
    for (int j = 0; j < 16; j++) {
      const int dd = (ty << 4) + j;
      g_ebT[((d0 + dd) << 10) + k0 + tx] = tl[tx][dd];
    }
  }
}

// main: 64 tokens/block, 512 threads (8 waves, k split 8 ways -> 16 waves/CU).
// Scores carry k in low-10 mantissa bits; top-2 via med3/max (no index VALU).
__global__ __launch_bounds__(512, 4) void vq_main(const float* __restrict__ x,
                                                  const float* __restrict__ emb,
                                                  float* __restrict__ out) {
  __shared__ __align__(16) _Float16 zt[64 * 256];   // 32 KB, XOR-swizzled
  __shared__ float ckl[K_CB];
  __shared__ float wv1[8][64], wv2[8][64];
  __shared__ int   fidx[64];
  __shared__ float lred[8];

  const int tid = threadIdx.x;
  const int n0  = blockIdx.x * 64;
  const int b   = blockIdx.x >> 4;
  const int hw0 = (blockIdx.x & 15) << 6;

  ckl[tid] = g_ck[tid];
  ckl[tid + 512] = g_ck[tid + 512];

  // stage x tile -> fp16; (n,d) at n*256 + (((d>>3)^(n&7)^(n>>3))<<3) + (d&7)
  {
    const int hw8 = (tid & 7) << 3;
    const int dl  = tid >> 3;               // 0..63
    #pragma unroll
    for (int it = 0; it < 4; it++) {
      const int d = (it << 6) + dl;
      const float* src = x + (((b << 8) + d) << 10) + hw0 + hw8;
      f32x4 a0 = *(const f32x4*)src;
      f32x4 a1 = *(const f32x4*)(src + 4);
      _Float16 cv[8];
      cv[0]=(_Float16)a0[0]; cv[1]=(_Float16)a0[1]; cv[2]=(_Float16)a0[2]; cv[3]=(_Float16)a0[3];
      cv[4]=(_Float16)a1[0]; cv[5]=(_Float16)a1[1]; cv[6]=(_Float16)a1[2]; cv[7]=(_Float16)a1[3];
      const int blkx = d >> 3;
      #pragma unroll
      for (int i = 0; i < 8; i++) {
        const int n   = hw8 + i;
        const int blk = blkx ^ i ^ (tid & 7);
        zt[(n << 8) + (blk << 3) + (d & 7)] = cv[i];
      }
    }
  }
  __syncthreads();

  const int w = tid >> 6;    // wave 0..7, owns codes [w*128, w*128+128)
  const int l = tid & 63;
  const int c = l & 15;
  const int q = l >> 4;

  float v1[4][4], v2[4][4];
  #pragma unroll
  for (int t = 0; t < 4; t++)
    #pragma unroll
    for (int r = 0; r < 4; r++) { v1[t][r] = -3.0e38f; v2[t][r] = -3.0e38f; }

  #pragma unroll 1
  for (int mac = 0; mac < 4; mac++) {
    const int base = (w << 7) + (mac << 5);          // 32 codes per macro
    const float ck0 = ckl[base + c];
    const float ck1 = ckl[base + 16 + c];
    f32x4 acc[4][2];
    #pragma unroll
    for (int t = 0; t < 4; t++) {
      acc[t][0] = f32x4{-ck0, -ck0, -ck0, -ck0};
      acc[t][1] = f32x4{-ck1, -ck1, -ck1, -ck1};
    }
    #pragma unroll
    for (int s = 0; s < 8; s++) {
      const half8 b0 = *(const half8*)(g_eh + ((base + c) << 8) + (s << 5) + (q << 3));
      const half8 b1 = *(const half8*)(g_eh + ((base + 16 + c) << 8) + (s << 5) + (q << 3));
      #pragma unroll
      for (int t = 0; t < 4; t++) {
        const int n  = (t << 4) + c;
        const int sw = (n & 7) ^ (n >> 3);
        const half8 a = *(const half8*)(zt + (n << 8) + ((((s << 2) + q) ^ sw) << 3));
        acc[t][0] = __builtin_amdgcn_mfma_f32_16x16x32_f16(a, b0, acc[t][0], 0, 0, 0);
        acc[t][1] = __builtin_amdgcn_mfma_f32_16x16x32_f16(a, b1, acc[t][1], 0, 0, 0);
      }
    }
    #pragma unroll
    for (int t = 0; t < 4; t++)
      #pragma unroll
      for (int r = 0; r < 4; r++)
        #pragma unroll
        for (int kc = 0; kc < 2; kc++) {
          const unsigned kk = (unsigned)(base + (kc << 4) + c);
          const unsigned su = (__float_as_uint(acc[t][kc][r]) & 0xFFFFFC00u) | kk;
          const float se = __uint_as_float(su);
          v2[t][r] = __builtin_amdgcn_fmed3f(se, v1[t][r], v2[t][r]);
          v1[t][r] = fmaxf(se, v1[t][r]);
        }
  }

  // top-2 merge across the 16 column lanes (codes differ per c), then across waves
  #pragma unroll
  for (int t = 0; t < 4; t++)
    #pragma unroll
    for (int r = 0; r < 4; r++) {
      float a1 = v1[t][r], a2 = v2[t][r];
      #pragma unroll
      for (int m = 1; m < 16; m <<= 1) {
        const float o1 = __shfl_xor(a1, m);
        const float o2 = __shfl_xor(a2, m);
        a2 = fmaxf(fminf(a1, o1), fmaxf(a2, o2));
        a1 = fmaxf(a1, o1);
      }
      if (c == 0) {
        const int nl = (t << 4) + (q << 2) + r;
        wv1[w][nl] = a1; wv2[w][nl] = a2;
      }
    }
  __syncthreads();

  if (tid < 64) {
    float a1 = wv1[0][tid], a2 = wv2[0][tid];
    #pragma unroll
    for (int ww = 1; ww < 8; ww++) {
      const float o1 = wv1[ww][tid], o2 = wv2[ww][tid];
      a2 = fmaxf(fminf(a1, o1), fmaxf(a2, o2));
      a1 = fmaxf(a1, o1);
    }
    const int ki = (int)(__float_as_uint(a1) & 1023u);
    fidx[tid] = ki;
    out[ZQ_ELEMS + n0 + tid] = (float)ki;
    if (a1 - a2 < TAU) {                       // ambiguous -> np-replicated pass 2
      int p = atomicAdd(&g_cnt, 1);
      if (p < FLAG_CAP) g_flags[p] = n0 + tid;
    }
  }
  __syncthreads();

  // gather e[idx] (f32), write z_quant f32 (coalesced over hw), accumulate loss
  float lacc = 0.0f;
  {
    const int hw = l;
    const int sw = (hw & 7) ^ (hw >> 3);
    const float* erow = emb + (fidx[hw] << 8);
    #pragma unroll
    for (int it = 0; it < 4; it++) {
      const int dblk = (it << 3) + w;            // 8 waves own disjoint dblk groups
      half8 zv = *(const half8*)(zt + (hw << 8) + ((dblk ^ sw) << 3));
      f32x4 e0 = *(const f32x4*)(erow + (dblk << 3));
      f32x4 e1 = *(const f32x4*)(erow + (dblk << 3) + 4);
      #pragma unroll
      for (int j = 0; j < 8; j++) {
        const int d = (dblk << 3) + j;
        const float ef = (j < 4) ? e0[j] : e1[j - 4];
        const float df = ef - (float)zv[j];
        lacc += df * df;
        out[(((b << 8) + d) << 10) + hw0 + hw] = ef;
      }
    }
  }
  #pragma unroll
  for (int m = 1; m < 64; m <<= 1) lacc += __shfl_xor(lacc, m);
  if (l == 0) lred[w] = lacc;
  __syncthreads();
  if (tid == 0) {
    float s = 0.0f;
    #pragma unroll
    for (int ww = 0; ww < 8; ww++) s += lred[ww];
    atomicAdd(&g_loss, s);
  }
}

// stage flagged tokens: uncoalesced x-gather ONCE per token -> coalesced g_zst row;
// A_n with the SAME 32-lane f64 tree op order as the passing rounds.
__global__ __launch_bounds__(256) void vq_stage(const float* __restrict__ x) {
  __shared__ float zl[256];
  const int tid = threadIdx.x;
  int cnt = g_cnt; if (cnt > FLAG_CAP) cnt = FLAG_CAP;
  for (int s = blockIdx.x; s < cnt; s += gridDim.x) {
    const int n = g_flags[s], b = n >> 10, hw = n & 1023;
    const float zv = x[(((b << 8) + tid) << 10) + hw];
    g_zst[(s << 8) + tid] = zv;
    zl[tid] = zv;
    __syncthreads();
    if (tid < 32) {
      double sa = 0.0;
      #pragma unroll
      for (int j = 0; j < 8; j++) { const double z = (double)zl[(tid << 3) + j]; sa += z * z; }
      #pragma unroll
      for (int m = 1; m < 32; m <<= 1) sa += __shfl_xor(sa, m);
      if (tid == 0) g_aA[s] = (float)sa;
    }
    __syncthreads();
  }
}

// pass 2: replicate np f32 distance D = fl32(fl32(A_n + B_k) - 2*fl32(C_nk)).
// job = (token-pair, r-quarter); lane owns k = r*256+tid (d-ascending f64 chain,
// bit-identical to passing rounds); block tree -> one atomicMin/token.
__global__ __launch_bounds__(256) void vq_fix() {
  __shared__ float z0l[256], z1l[256];
  __shared__ float bvv[2][256];
  __shared__ int   bkk[2][256];
  const int tid = threadIdx.x;
  int cnt = g_cnt; if (cnt > FLAG_CAP) cnt = FLAG_CAP;
  const int njob = ((cnt + 1) >> 1) << 2;
  for (int j = blockIdx.x; j < njob; j += gridDim.x) {
    const int pr = j >> 2, r = j & 3;
    const int s0 = pr << 1;
    const int s1 = (s0 + 1 < cnt) ? s0 + 1 : cnt - 1;
    z0l[tid] = g_zst[(s0 << 8) + tid];
    z1l[tid] = g_zst[(s1 << 8) + tid];
    __syncthreads();
    double c0 = 0.0, c1 = 0.0;
    const float* colbase = g_ebT + (r << 8) + tid;
    #pragma unroll 8
    for (int d = 0; d < 256; d++) {
      const double e = (double)colbase[d << 10];    // coalesced over tid
      c0 = fma(e, (double)z0l[d], c0);
      c1 = fma(e, (double)z1l[d], c1);
    }
    const int k = (r << 8) + tid;
    const float bkv = g_bk[k];
    bvv[0][tid] = (g_aA[s0] + bkv) - 2.0f * (float)c0;
    bkk[0][tid] = k;
    bvv[1][tid] = (g_aA[s1] + bkv) - 2.0f * (float)c1;
    bkk[1][tid] = k;
    __syncthreads();
    for (int off = 128; off >= 1; off >>= 1) {
      if (tid < off) {
        #pragma unroll
        for (int g = 0; g < 2; g++) {
          const float v2c = bvv[g][tid + off]; const int k2 = bkk[g][tid + off];
          if (v2c < bvv[g][tid] || (v2c == bvv[g][tid] && k2 < bkk[g][tid])) {
            bvv[g][tid] = v2c; bkk[g][tid] = k2;
          }
        }
      }
      __syncthreads();
    }
    if (tid == 0) {
      atomicMin(&g_best[s0], enc_dk(bvv[0][0], bkk[0][0]));
      atomicMin(&g_best[s1], enc_dk(bvv[1][0], bkk[1][0]));
    }
    __syncthreads();
  }
}

// decode winners + loss finalize (fused)
__global__ __launch_bounds__(256) void vq_outfin(float* __restrict__ out) {
  int cnt = g_cnt; if (cnt > FLAG_CAP) cnt = FLAG_CAP;
  for (int s = blockIdx.x * 256 + threadIdx.x; s < cnt; s += gridDim.x * 256)
    out[ZQ_ELEMS + g_flags[s]] = (float)(unsigned int)(g_best[s] & 0xFFFFFFFFu);
  if (blockIdx.x == 0 && threadIdx.x == 0)
    out[ZQ_ELEMS + N_TOK] = g_loss * (1.25f / 8388608.0f);
}

extern "C" void kernel_launch(void* const* d_in, const int* in_sizes, int n_in,
                              void* d_out, int out_size, void* d_ws, size_t ws_size,
                              hipStream_t stream) {
  const float* x   = (const float*)d_in[0];
  const float* emb = (const float*)d_in[1];
  float* out = (float*)d_out;
  vq_prep_tr<<<320, 256, 0, stream>>>(emb);
  vq_main<<<512, 512, 0, stream>>>(x, emb, out);
  vq_stage<<<1024, 256, 0, stream>>>(x);
  vq_fix<<<2048, 256, 0, stream>>>();
  vq_outfin<<<32, 256, 0, stream>>>(out);
}